// Round 7
// baseline (1436.669 us; speedup 1.0000x reference)
//
#include <hip/hip_runtime.h>

#define NV 50000
#define NE 5000
#define NC 16
#define TAU_INV 2.0f
#define EPS 1e-8f

#define NCH 200         // v-chunks
#define VCH 250         // NV / NCH ; LDS slice = 250*32*4 = 31.25 KB
#define GRP 5           // h-load ring depth (250 % 5 == 0)
#define NXB 10          // x-blocks; 10*256 lanes * 2 edges = 5120 slots >= 5000
#define NLANE 5120

// ---------------- softmax: one thread per row, both pred_s and pred_t.
// Output layout: p[v][32] = [softmax(pred_s[v]) (16) | softmax(pred_t[v]) (16)]
__global__ __launch_bounds__(256) void softmax_kernel(
    const float* __restrict__ pred_s, const float* __restrict__ pred_t,
    float* __restrict__ p) {
  int i = blockIdx.x * 256 + threadIdx.x;
  if (i >= 2 * NV) return;
  const float* src;
  float* dst;
  if (i < NV) { src = pred_s + (size_t)i * NC; dst = p + (size_t)i * 32; }
  else        { int j = i - NV; src = pred_t + (size_t)j * NC; dst = p + (size_t)j * 32 + 16; }
  float4 a = ((const float4*)src)[0];
  float4 b = ((const float4*)src)[1];
  float4 c = ((const float4*)src)[2];
  float4 d = ((const float4*)src)[3];
  float x[16] = {a.x,a.y,a.z,a.w, b.x,b.y,b.z,b.w, c.x,c.y,c.z,c.w, d.x,d.y,d.z,d.w};
  float mx = x[0];
#pragma unroll
  for (int k = 1; k < 16; ++k) mx = fmaxf(mx, x[k]);
  float sum = 0.f;
#pragma unroll
  for (int k = 0; k < 16; ++k) { x[k] = expf(x[k] - mx); sum += x[k]; }
  float inv = 1.f / sum;
#pragma unroll
  for (int k = 0; k < 16; ++k) x[k] *= inv;
  float4 o0 = {x[0], x[1], x[2], x[3]};
  float4 o1 = {x[4], x[5], x[6], x[7]};
  float4 o2 = {x[8], x[9], x[10], x[11]};
  float4 o3 = {x[12], x[13], x[14], x[15]};
  ((float4*)dst)[0] = o0;
  ((float4*)dst)[1] = o1;
  ((float4*)dst)[2] = o2;
  ((float4*)dst)[3] = o3;
}

// ---------------- main accumulation, 2 edges per lane (float2 H loads).
// LDS broadcast reads are per-WAVE, so 2 edges/lane halves the per-CU LDS
// instruction count (the R6 bottleneck) while keeping VGPRs ~110 (no spill).
// part layout (floats): part[y][k][NLANE], k: 0..15 = S, 16..31 = T, 32 = deg
__global__ __launch_bounds__(256) void accum_kernel(
    const float* __restrict__ H, const float* __restrict__ p,
    float* __restrict__ part) {
  __shared__ float lp[VCH * 32];   // 31.25 KB
  int xb = blockIdx.x;
  int y  = blockIdx.y;
  int e0 = 2 * (xb * 256 + (int)threadIdx.x);
  if (e0 > NE - 2) e0 = NE - 2;   // dup lanes write identical values: benign
  int v0 = y * VCH;

  // stage the p slice (contiguous 32 KB) into LDS, coalesced float4
  {
    const float4* __restrict__ src = (const float4*)(p + (size_t)v0 * 32);
    float4* dst = (float4*)lp;
    for (int i = threadIdx.x; i < VCH * 8; i += 256) dst[i] = src[i];
  }
  __syncthreads();

  float2 aS[16], aT[16], dg;
#pragma unroll
  for (int k = 0; k < 16; ++k) {
    aS[k] = make_float2(0.f, 0.f);
    aT[k] = make_float2(0.f, 0.f);
  }
  dg = make_float2(0.f, 0.f);

  const float* __restrict__ hp = H + (size_t)v0 * NE + e0;

  float2 hc[GRP];
#pragma unroll
  for (int u = 0; u < GRP; ++u)
    hc[u] = *(const float2*)(hp + (size_t)u * NE);

  for (int vb = 0; vb < VCH; vb += GRP) {
    int nb = (vb + GRP < VCH) ? vb + GRP : vb;   // last iter: benign re-load
    float2 hn[GRP];
#pragma unroll
    for (int u = 0; u < GRP; ++u)
      hn[u] = *(const float2*)(hp + (size_t)(nb + u) * NE);

#pragma unroll
    for (int u = 0; u < GRP; ++u) {
      const float4* __restrict__ r = (const float4*)(lp + (size_t)(vb + u) * 32);
      float2 h = hc[u];
      dg.x += h.x; dg.y += h.y;
      // s-half first, then t-half: caps live float temps at ~16
      {
        float4 s0 = r[0], s1 = r[1], s2 = r[2], s3 = r[3];
        float sv[16] = {s0.x,s0.y,s0.z,s0.w, s1.x,s1.y,s1.z,s1.w,
                        s2.x,s2.y,s2.z,s2.w, s3.x,s3.y,s3.z,s3.w};
#pragma unroll
        for (int k = 0; k < 16; ++k) {
          aS[k].x = fmaf(h.x, sv[k], aS[k].x);
          aS[k].y = fmaf(h.y, sv[k], aS[k].y);
        }
      }
      {
        float4 t0 = r[4], t1 = r[5], t2 = r[6], t3 = r[7];
        float tv[16] = {t0.x,t0.y,t0.z,t0.w, t1.x,t1.y,t1.z,t1.w,
                        t2.x,t2.y,t2.z,t2.w, t3.x,t3.y,t3.z,t3.w};
#pragma unroll
        for (int k = 0; k < 16; ++k) {
          aT[k].x = fmaf(h.x, tv[k], aT[k].x);
          aT[k].y = fmaf(h.y, tv[k], aT[k].y);
        }
      }
    }
#pragma unroll
    for (int u = 0; u < GRP; ++u) hc[u] = hn[u];
  }

  float* op = part + (size_t)y * 33 * NLANE + e0;
#pragma unroll
  for (int k = 0; k < 16; ++k)
    *(float2*)(op + (size_t)k * NLANE) = aS[k];
#pragma unroll
  for (int k = 0; k < 16; ++k)
    *(float2*)(op + (size_t)(16 + k) * NLANE) = aT[k];
  *(float2*)(op + (size_t)32 * NLANE) = dg;
}

// ---------------- reduce the NCH partials: acc[k][NLANE] = sum_y part[y][k][NLANE]
__global__ __launch_bounds__(256) void reduce_kernel(
    const float* __restrict__ part, float* __restrict__ acc) {
  int i = blockIdx.x * 256 + threadIdx.x;
  if (i >= 33 * NLANE) return;
  float s = 0.f;
#pragma unroll 4
  for (int y = 0; y < NCH; ++y) s += part[(size_t)y * 33 * NLANE + i];
  acc[i] = s;
}

// ---------------- per-edge KL + masked reduction (single block, 256 threads)
// acc layout: acc[k*NLANE + e]; S at k, T at 16+k, deg at 32
__global__ __launch_bounds__(256) void kl_kernel(
    const float* __restrict__ acc, const unsigned char* __restrict__ e_mask,
    float* __restrict__ out) {
  __shared__ float snum[4];
  __shared__ float scnt[4];
  int t = threadIdx.x;
  float num = 0.f, cnt = 0.f;
  for (int e = t; e < NE; e += 256) {
    if (e_mask[e]) {
      float deg = acc[(size_t)32 * NLANE + e];
      float invd = 1.f / deg;
      float kl = 0.f;
#pragma unroll
      for (int k = 0; k < 16; ++k) {
        float ms = acc[(size_t)k * NLANE + e] * invd;
        float mt = acc[(size_t)(16 + k) * NLANE + e] * invd;
        float xs = ms * TAU_INV + EPS;
        float xt = mt * TAU_INV + EPS;
        kl += xt * (logf(xt) - logf(xs));
      }
      num += kl;
      cnt += 1.f;
    }
  }
#pragma unroll
  for (int off = 32; off > 0; off >>= 1) {
    num += __shfl_down(num, off, 64);
    cnt += __shfl_down(cnt, off, 64);
  }
  if ((t & 63) == 0) { snum[t >> 6] = num; scnt[t >> 6] = cnt; }
  __syncthreads();
  if (t == 0) {
    float n = snum[0] + snum[1] + snum[2] + snum[3];
    float c2 = scnt[0] + scnt[1] + scnt[2] + scnt[3];
    out[0] = n / fmaxf(c2, 1.f);
  }
}

extern "C" void kernel_launch(void* const* d_in, const int* in_sizes, int n_in,
                              void* d_out, int out_size, void* d_ws, size_t ws_size,
                              hipStream_t stream) {
  const float* pred_s = (const float*)d_in[0];
  const float* pred_t = (const float*)d_in[1];
  const float* H      = (const float*)d_in[2];
  const unsigned char* e_mask = (const unsigned char*)d_in[3];

  float* ws   = (float*)d_ws;
  float* p    = ws;                                    // NV*32         (6.40 MB)
  float* acc  = ws + (size_t)NV * 32;                  // 33*NLANE      (0.68 MB)
  float* part = acc + (size_t)33 * NLANE;              // NCH*33*NLANE  (135 MB)

  softmax_kernel<<<dim3((2 * NV + 255) / 256), 256, 0, stream>>>(pred_s, pred_t, p);
  accum_kernel<<<dim3(NXB, NCH), 256, 0, stream>>>(H, p, part);
  reduce_kernel<<<dim3((33 * NLANE + 255) / 256), 256, 0, stream>>>(part, acc);
  kl_kernel<<<1, 256, 0, stream>>>(acc, e_mask, (float*)d_out);
}

// Round 8
// 1427.287 us; speedup vs baseline: 1.0066x; 1.0066x over previous
//
#include <hip/hip_runtime.h>

#define NV 50000
#define NE 5000
#define NC 16
#define TAU_INV 2.0f
#define EPS 1e-8f

#define NCH 200         // v-chunks
#define VCH 250         // NV / NCH ; LDS slice = 250*32*4 = 31.25 KB
#define GRP 2           // h-load ring depth (250 % 2 == 0); 2 KB/wave in flight
#define NXB 5           // x-blocks; 5 * 256 lanes * 4 edges = 5120 slots >= 5000
#define NLANE 5120

// ---------------- softmax: one thread per row, both pred_s and pred_t.
// Output layout: p[v][32] = [softmax(pred_s[v]) (16) | softmax(pred_t[v]) (16)]
__global__ __launch_bounds__(256) void softmax_kernel(
    const float* __restrict__ pred_s, const float* __restrict__ pred_t,
    float* __restrict__ p) {
  int i = blockIdx.x * 256 + threadIdx.x;
  if (i >= 2 * NV) return;
  const float* src;
  float* dst;
  if (i < NV) { src = pred_s + (size_t)i * NC; dst = p + (size_t)i * 32; }
  else        { int j = i - NV; src = pred_t + (size_t)j * NC; dst = p + (size_t)j * 32 + 16; }
  float4 a = ((const float4*)src)[0];
  float4 b = ((const float4*)src)[1];
  float4 c = ((const float4*)src)[2];
  float4 d = ((const float4*)src)[3];
  float x[16] = {a.x,a.y,a.z,a.w, b.x,b.y,b.z,b.w, c.x,c.y,c.z,c.w, d.x,d.y,d.z,d.w};
  float mx = x[0];
#pragma unroll
  for (int k = 1; k < 16; ++k) mx = fmaxf(mx, x[k]);
  float sum = 0.f;
#pragma unroll
  for (int k = 0; k < 16; ++k) { x[k] = expf(x[k] - mx); sum += x[k]; }
  float inv = 1.f / sum;
#pragma unroll
  for (int k = 0; k < 16; ++k) x[k] *= inv;
  float4 o0 = {x[0], x[1], x[2], x[3]};
  float4 o1 = {x[4], x[5], x[6], x[7]};
  float4 o2 = {x[8], x[9], x[10], x[11]};
  float4 o3 = {x[12], x[13], x[14], x[15]};
  ((float4*)dst)[0] = o0;
  ((float4*)dst)[1] = o1;
  ((float4*)dst)[2] = o2;
  ((float4*)dst)[3] = o3;
}

// ---------------- main accumulation, 4 edges per lane (float4 H loads).
// The session invariant (R1/R4/R6/R7 all ~equal) shows the bottleneck is the
// H DRAM pattern: short per-walker segments at 20 KB row stride. This block
// shape reads 4 KB contiguous per row (vs 512 B in R7) with ~half the
// concurrent walkers. NO launch_bounds occupancy arg: R5 proved (256,2)
// clamps VGPR to 128 and spills 1.9 GB; unconstrained (R6) does not spill.
// part layout (floats): part[y][k][NLANE], k: 0..15 = S, 16..31 = T, 32 = deg
__global__ __launch_bounds__(256) void accum_kernel(
    const float* __restrict__ H, const float* __restrict__ p,
    float* __restrict__ part) {
  __shared__ float lp[VCH * 32];   // 31.25 KB
  int xb = blockIdx.x;
  int y  = blockIdx.y;
  int e0 = 4 * (xb * 256 + (int)threadIdx.x);
  if (e0 > NE - 4) e0 = NE - 4;   // dup lanes write identical values: benign
  int v0 = y * VCH;

  // stage the p slice (contiguous 32 KB) into LDS, coalesced float4
  {
    const float4* __restrict__ src = (const float4*)(p + (size_t)v0 * 32);
    float4* dst = (float4*)lp;
    for (int i = threadIdx.x; i < VCH * 8; i += 256) dst[i] = src[i];
  }
  __syncthreads();

  float4 aS[16], aT[16], dg;
#pragma unroll
  for (int k = 0; k < 16; ++k) {
    aS[k] = make_float4(0.f, 0.f, 0.f, 0.f);
    aT[k] = make_float4(0.f, 0.f, 0.f, 0.f);
  }
  dg = make_float4(0.f, 0.f, 0.f, 0.f);

  const float* __restrict__ hp = H + (size_t)v0 * NE + e0;

  float4 hc[GRP];
#pragma unroll
  for (int u = 0; u < GRP; ++u)
    hc[u] = *(const float4*)(hp + (size_t)u * NE);

  for (int vb = 0; vb < VCH; vb += GRP) {
    int nb = (vb + GRP < VCH) ? vb + GRP : vb;   // last iter: benign re-load
    float4 hn[GRP];
#pragma unroll
    for (int u = 0; u < GRP; ++u)
      hn[u] = *(const float4*)(hp + (size_t)(nb + u) * NE);

#pragma unroll
    for (int u = 0; u < GRP; ++u) {
      const float4* __restrict__ r = (const float4*)(lp + (size_t)(vb + u) * 32);
      float4 h = hc[u];
      dg.x += h.x; dg.y += h.y; dg.z += h.z; dg.w += h.w;
      // s-half then t-half: caps live LDS temps at 16 floats
      {
        float4 s0 = r[0], s1 = r[1], s2 = r[2], s3 = r[3];
        float sv[16] = {s0.x,s0.y,s0.z,s0.w, s1.x,s1.y,s1.z,s1.w,
                        s2.x,s2.y,s2.z,s2.w, s3.x,s3.y,s3.z,s3.w};
#pragma unroll
        for (int k = 0; k < 16; ++k) {
          aS[k].x = fmaf(h.x, sv[k], aS[k].x);
          aS[k].y = fmaf(h.y, sv[k], aS[k].y);
          aS[k].z = fmaf(h.z, sv[k], aS[k].z);
          aS[k].w = fmaf(h.w, sv[k], aS[k].w);
        }
      }
      {
        float4 t0 = r[4], t1 = r[5], t2 = r[6], t3 = r[7];
        float tv[16] = {t0.x,t0.y,t0.z,t0.w, t1.x,t1.y,t1.z,t1.w,
                        t2.x,t2.y,t2.z,t2.w, t3.x,t3.y,t3.z,t3.w};
#pragma unroll
        for (int k = 0; k < 16; ++k) {
          aT[k].x = fmaf(h.x, tv[k], aT[k].x);
          aT[k].y = fmaf(h.y, tv[k], aT[k].y);
          aT[k].z = fmaf(h.z, tv[k], aT[k].z);
          aT[k].w = fmaf(h.w, tv[k], aT[k].w);
        }
      }
    }
#pragma unroll
    for (int u = 0; u < GRP; ++u) hc[u] = hn[u];
  }

  float* op = part + (size_t)y * 33 * NLANE + e0;
#pragma unroll
  for (int k = 0; k < 16; ++k)
    *(float4*)(op + (size_t)k * NLANE) = aS[k];
#pragma unroll
  for (int k = 0; k < 16; ++k)
    *(float4*)(op + (size_t)(16 + k) * NLANE) = aT[k];
  *(float4*)(op + (size_t)32 * NLANE) = dg;
}

// ---------------- reduce the NCH partials: acc[k][NLANE] = sum_y part[y][k][NLANE]
__global__ __launch_bounds__(256) void reduce_kernel(
    const float* __restrict__ part, float* __restrict__ acc) {
  int i = blockIdx.x * 256 + threadIdx.x;
  if (i >= 33 * NLANE) return;
  float s = 0.f;
#pragma unroll 4
  for (int y = 0; y < NCH; ++y) s += part[(size_t)y * 33 * NLANE + i];
  acc[i] = s;
}

// ---------------- per-edge KL + masked reduction (single block, 256 threads)
// acc layout: acc[k*NLANE + e]; S at k, T at 16+k, deg at 32
__global__ __launch_bounds__(256) void kl_kernel(
    const float* __restrict__ acc, const unsigned char* __restrict__ e_mask,
    float* __restrict__ out) {
  __shared__ float snum[4];
  __shared__ float scnt[4];
  int t = threadIdx.x;
  float num = 0.f, cnt = 0.f;
  for (int e = t; e < NE; e += 256) {
    if (e_mask[e]) {
      float deg = acc[(size_t)32 * NLANE + e];
      float invd = 1.f / deg;
      float kl = 0.f;
#pragma unroll
      for (int k = 0; k < 16; ++k) {
        float ms = acc[(size_t)k * NLANE + e] * invd;
        float mt = acc[(size_t)(16 + k) * NLANE + e] * invd;
        float xs = ms * TAU_INV + EPS;
        float xt = mt * TAU_INV + EPS;
        kl += xt * (logf(xt) - logf(xs));
      }
      num += kl;
      cnt += 1.f;
    }
  }
#pragma unroll
  for (int off = 32; off > 0; off >>= 1) {
    num += __shfl_down(num, off, 64);
    cnt += __shfl_down(cnt, off, 64);
  }
  if ((t & 63) == 0) { snum[t >> 6] = num; scnt[t >> 6] = cnt; }
  __syncthreads();
  if (t == 0) {
    float n = snum[0] + snum[1] + snum[2] + snum[3];
    float c2 = scnt[0] + scnt[1] + scnt[2] + scnt[3];
    out[0] = n / fmaxf(c2, 1.f);
  }
}

extern "C" void kernel_launch(void* const* d_in, const int* in_sizes, int n_in,
                              void* d_out, int out_size, void* d_ws, size_t ws_size,
                              hipStream_t stream) {
  const float* pred_s = (const float*)d_in[0];
  const float* pred_t = (const float*)d_in[1];
  const float* H      = (const float*)d_in[2];
  const unsigned char* e_mask = (const unsigned char*)d_in[3];

  float* ws   = (float*)d_ws;
  float* p    = ws;                                    // NV*32         (6.40 MB)
  float* acc  = ws + (size_t)NV * 32;                  // 33*NLANE      (0.68 MB)
  float* part = acc + (size_t)33 * NLANE;              // NCH*33*NLANE  (135 MB)

  softmax_kernel<<<dim3((2 * NV + 255) / 256), 256, 0, stream>>>(pred_s, pred_t, p);
  accum_kernel<<<dim3(NXB, NCH), 256, 0, stream>>>(H, p, part);
  reduce_kernel<<<dim3((33 * NLANE + 255) / 256), 256, 0, stream>>>(part, acc);
  kl_kernel<<<1, 256, 0, stream>>>(acc, e_mask, (float*)d_out);
}

// Round 10
// 1385.470 us; speedup vs baseline: 1.0370x; 1.0302x over previous
//
#include <hip/hip_runtime.h>

#define NV 50000
#define NE 5000
#define NC 16
#define TAU_INV 2.0f
#define EPS 1e-8f

#define NCH 200         // v-chunks
#define VCH 250         // NV / NCH ; LDS slice = 250*32*4 = 31.25 KB
#define GRP 2           // h-load ring depth (250 % 2 == 0)
#define NXB 5           // x-blocks; 5 * 256 lanes * 4 edges = 5120 slots >= 5000
#define NBLK (NXB * NCH)
#define NLANE 5120

// native vector type for nontemporal builtins (HIP_vector_type is rejected)
typedef float vf4 __attribute__((ext_vector_type(4)));

// ---------------- softmax: one thread per row, both pred_s and pred_t.
// Output layout: p[v][32] = [softmax(pred_s[v]) (16) | softmax(pred_t[v]) (16)]
__global__ __launch_bounds__(256) void softmax_kernel(
    const float* __restrict__ pred_s, const float* __restrict__ pred_t,
    float* __restrict__ p) {
  int i = blockIdx.x * 256 + threadIdx.x;
  if (i >= 2 * NV) return;
  const float* src;
  float* dst;
  if (i < NV) { src = pred_s + (size_t)i * NC; dst = p + (size_t)i * 32; }
  else        { int j = i - NV; src = pred_t + (size_t)j * NC; dst = p + (size_t)j * 32 + 16; }
  float4 a = ((const float4*)src)[0];
  float4 b = ((const float4*)src)[1];
  float4 c = ((const float4*)src)[2];
  float4 d = ((const float4*)src)[3];
  float x[16] = {a.x,a.y,a.z,a.w, b.x,b.y,b.z,b.w, c.x,c.y,c.z,c.w, d.x,d.y,d.z,d.w};
  float mx = x[0];
#pragma unroll
  for (int k = 1; k < 16; ++k) mx = fmaxf(mx, x[k]);
  float sum = 0.f;
#pragma unroll
  for (int k = 0; k < 16; ++k) { x[k] = expf(x[k] - mx); sum += x[k]; }
  float inv = 1.f / sum;
#pragma unroll
  for (int k = 0; k < 16; ++k) x[k] *= inv;
  float4 o0 = {x[0], x[1], x[2], x[3]};
  float4 o1 = {x[4], x[5], x[6], x[7]};
  float4 o2 = {x[8], x[9], x[10], x[11]};
  float4 o3 = {x[12], x[13], x[14], x[15]};
  ((float4*)dst)[0] = o0;
  ((float4*)dst)[1] = o1;
  ((float4*)dst)[2] = o2;
  ((float4*)dst)[3] = o3;
}

// ---------------- main accumulation, 4 edges per lane, NONTEMPORAL H stream.
// H has zero reuse: nt loads skip cache allocation (hypothesis for the
// persistent ~2x-over-floor stream BW). Grid flattened; XCD swizzle (b&7
// heuristic) gives each XCD a contiguous slab of H rows.
// part layout (floats): part[y][k][NLANE], k: 0..15 = S, 16..31 = T, 32 = deg
__global__ __launch_bounds__(256) void accum_kernel(
    const float* __restrict__ H, const float* __restrict__ p,
    float* __restrict__ part) {
  __shared__ float lp[VCH * 32];   // 31.25 KB
  int b = blockIdx.x;
  int xcd   = b & 7;
  int local = b >> 3;
  int item  = xcd * (NBLK / 8) + local;   // contiguous item span per XCD
  int xb = item % NXB;
  int y  = item / NXB;
  int e0 = 4 * (xb * 256 + (int)threadIdx.x);
  if (e0 > NE - 4) e0 = NE - 4;   // dup lanes write identical values: benign
  int v0 = y * VCH;

  // stage the p slice (contiguous 32 KB) into LDS, coalesced float4
  {
    const float4* __restrict__ src = (const float4*)(p + (size_t)v0 * 32);
    float4* dst = (float4*)lp;
    for (int i = threadIdx.x; i < VCH * 8; i += 256) dst[i] = src[i];
  }
  __syncthreads();

  float4 aS[16], aT[16], dg;
#pragma unroll
  for (int k = 0; k < 16; ++k) {
    aS[k] = make_float4(0.f, 0.f, 0.f, 0.f);
    aT[k] = make_float4(0.f, 0.f, 0.f, 0.f);
  }
  dg = make_float4(0.f, 0.f, 0.f, 0.f);

  const float* __restrict__ hp = H + (size_t)v0 * NE + e0;

  vf4 hc[GRP];
#pragma unroll
  for (int u = 0; u < GRP; ++u)
    hc[u] = __builtin_nontemporal_load((const vf4*)(hp + (size_t)u * NE));

  for (int vb = 0; vb < VCH; vb += GRP) {
    int nb = (vb + GRP < VCH) ? vb + GRP : vb;   // last iter: benign re-load
    vf4 hn[GRP];
#pragma unroll
    for (int u = 0; u < GRP; ++u)
      hn[u] = __builtin_nontemporal_load((const vf4*)(hp + (size_t)(nb + u) * NE));

#pragma unroll
    for (int u = 0; u < GRP; ++u) {
      const float4* __restrict__ r = (const float4*)(lp + (size_t)(vb + u) * 32);
      vf4 h = hc[u];
      dg.x += h.x; dg.y += h.y; dg.z += h.z; dg.w += h.w;
      {
        float4 s0 = r[0], s1 = r[1], s2 = r[2], s3 = r[3];
        float sv[16] = {s0.x,s0.y,s0.z,s0.w, s1.x,s1.y,s1.z,s1.w,
                        s2.x,s2.y,s2.z,s2.w, s3.x,s3.y,s3.z,s3.w};
#pragma unroll
        for (int k = 0; k < 16; ++k) {
          aS[k].x = fmaf(h.x, sv[k], aS[k].x);
          aS[k].y = fmaf(h.y, sv[k], aS[k].y);
          aS[k].z = fmaf(h.z, sv[k], aS[k].z);
          aS[k].w = fmaf(h.w, sv[k], aS[k].w);
        }
      }
      {
        float4 t0 = r[4], t1 = r[5], t2 = r[6], t3 = r[7];
        float tv[16] = {t0.x,t0.y,t0.z,t0.w, t1.x,t1.y,t1.z,t1.w,
                        t2.x,t2.y,t2.z,t2.w, t3.x,t3.y,t3.z,t3.w};
#pragma unroll
        for (int k = 0; k < 16; ++k) {
          aT[k].x = fmaf(h.x, tv[k], aT[k].x);
          aT[k].y = fmaf(h.y, tv[k], aT[k].y);
          aT[k].z = fmaf(h.z, tv[k], aT[k].z);
          aT[k].w = fmaf(h.w, tv[k], aT[k].w);
        }
      }
    }
#pragma unroll
    for (int u = 0; u < GRP; ++u) hc[u] = hn[u];
  }

  float* op = part + (size_t)y * 33 * NLANE + e0;
#pragma unroll
  for (int k = 0; k < 16; ++k) {
    vf4 w = {aS[k].x, aS[k].y, aS[k].z, aS[k].w};
    __builtin_nontemporal_store(w, (vf4*)(op + (size_t)k * NLANE));
  }
#pragma unroll
  for (int k = 0; k < 16; ++k) {
    vf4 w = {aT[k].x, aT[k].y, aT[k].z, aT[k].w};
    __builtin_nontemporal_store(w, (vf4*)(op + (size_t)(16 + k) * NLANE));
  }
  {
    vf4 w = {dg.x, dg.y, dg.z, dg.w};
    __builtin_nontemporal_store(w, (vf4*)(op + (size_t)32 * NLANE));
  }
}

// ---------------- reduce the NCH partials: acc[k][NLANE] = sum_y part[y][k][NLANE]
__global__ __launch_bounds__(256) void reduce_kernel(
    const float* __restrict__ part, float* __restrict__ acc) {
  int i = blockIdx.x * 256 + threadIdx.x;
  if (i >= 33 * NLANE) return;
  float s = 0.f;
#pragma unroll 4
  for (int y = 0; y < NCH; ++y) s += part[(size_t)y * 33 * NLANE + i];
  acc[i] = s;
}

// ---------------- per-edge KL + masked reduction (single block, 256 threads)
// acc layout: acc[k*NLANE + e]; S at k, T at 16+k, deg at 32
__global__ __launch_bounds__(256) void kl_kernel(
    const float* __restrict__ acc, const unsigned char* __restrict__ e_mask,
    float* __restrict__ out) {
  __shared__ float snum[4];
  __shared__ float scnt[4];
  int t = threadIdx.x;
  float num = 0.f, cnt = 0.f;
  for (int e = t; e < NE; e += 256) {
    if (e_mask[e]) {
      float deg = acc[(size_t)32 * NLANE + e];
      float invd = 1.f / deg;
      float kl = 0.f;
#pragma unroll
      for (int k = 0; k < 16; ++k) {
        float ms = acc[(size_t)k * NLANE + e] * invd;
        float mt = acc[(size_t)(16 + k) * NLANE + e] * invd;
        float xs = ms * TAU_INV + EPS;
        float xt = mt * TAU_INV + EPS;
        kl += xt * (logf(xt) - logf(xs));
      }
      num += kl;
      cnt += 1.f;
    }
  }
#pragma unroll
  for (int off = 32; off > 0; off >>= 1) {
    num += __shfl_down(num, off, 64);
    cnt += __shfl_down(cnt, off, 64);
  }
  if ((t & 63) == 0) { snum[t >> 6] = num; scnt[t >> 6] = cnt; }
  __syncthreads();
  if (t == 0) {
    float n = snum[0] + snum[1] + snum[2] + snum[3];
    float c2 = scnt[0] + scnt[1] + scnt[2] + scnt[3];
    out[0] = n / fmaxf(c2, 1.f);
  }
}

extern "C" void kernel_launch(void* const* d_in, const int* in_sizes, int n_in,
                              void* d_out, int out_size, void* d_ws, size_t ws_size,
                              hipStream_t stream) {
  const float* pred_s = (const float*)d_in[0];
  const float* pred_t = (const float*)d_in[1];
  const float* H      = (const float*)d_in[2];
  const unsigned char* e_mask = (const unsigned char*)d_in[3];

  float* ws   = (float*)d_ws;
  float* p    = ws;                                    // NV*32         (6.40 MB)
  float* acc  = ws + (size_t)NV * 32;                  // 33*NLANE      (0.68 MB)
  float* part = acc + (size_t)33 * NLANE;              // NCH*33*NLANE  (135 MB)

  softmax_kernel<<<dim3((2 * NV + 255) / 256), 256, 0, stream>>>(pred_s, pred_t, p);
  accum_kernel<<<dim3(NBLK), 256, 0, stream>>>(H, p, part);
  reduce_kernel<<<dim3((33 * NLANE + 255) / 256), 256, 0, stream>>>(part, acc);
  kl_kernel<<<1, 256, 0, stream>>>(acc, e_mask, (float*)d_out);
}

// Round 11
// 1344.560 us; speedup vs baseline: 1.0685x; 1.0304x over previous
//
#include <hip/hip_runtime.h>

#define NV 50000
#define NE 5000
#define NC 16
#define TAU_INV 2.0f
#define EPS 1e-8f

#define NCH 100         // v-chunks (halved vs R10: halves the part round-trip)
#define VCH 500         // NV / NCH ; LDS slice = 500*32*4 = 62.5 KB (< 64 KB static)
#define GRP 2           // h-load ring depth (500 % 2 == 0)
#define NXB 5           // x-blocks; 5 * 256 lanes * 4 edges = 5120 slots >= 5000
#define NBLK (NXB * NCH)   // 500
#define NLANE 5120

// native vector type for nontemporal builtins (HIP_vector_type is rejected)
typedef float vf4 __attribute__((ext_vector_type(4)));

// ---------------- softmax: one thread per row, both pred_s and pred_t.
// Output layout: p[v][32] = [softmax(pred_s[v]) (16) | softmax(pred_t[v]) (16)]
__global__ __launch_bounds__(256) void softmax_kernel(
    const float* __restrict__ pred_s, const float* __restrict__ pred_t,
    float* __restrict__ p) {
  int i = blockIdx.x * 256 + threadIdx.x;
  if (i >= 2 * NV) return;
  const float* src;
  float* dst;
  if (i < NV) { src = pred_s + (size_t)i * NC; dst = p + (size_t)i * 32; }
  else        { int j = i - NV; src = pred_t + (size_t)j * NC; dst = p + (size_t)j * 32 + 16; }
  float4 a = ((const float4*)src)[0];
  float4 b = ((const float4*)src)[1];
  float4 c = ((const float4*)src)[2];
  float4 d = ((const float4*)src)[3];
  float x[16] = {a.x,a.y,a.z,a.w, b.x,b.y,b.z,b.w, c.x,c.y,c.z,c.w, d.x,d.y,d.z,d.w};
  float mx = x[0];
#pragma unroll
  for (int k = 1; k < 16; ++k) mx = fmaxf(mx, x[k]);
  float sum = 0.f;
#pragma unroll
  for (int k = 0; k < 16; ++k) { x[k] = expf(x[k] - mx); sum += x[k]; }
  float inv = 1.f / sum;
#pragma unroll
  for (int k = 0; k < 16; ++k) x[k] *= inv;
  float4 o0 = {x[0], x[1], x[2], x[3]};
  float4 o1 = {x[4], x[5], x[6], x[7]};
  float4 o2 = {x[8], x[9], x[10], x[11]};
  float4 o3 = {x[12], x[13], x[14], x[15]};
  ((float4*)dst)[0] = o0;
  ((float4*)dst)[1] = o1;
  ((float4*)dst)[2] = o2;
  ((float4*)dst)[3] = o3;
}

// ---------------- main accumulation, 4 edges per lane, nontemporal H stream,
// XCD-slab swizzle. part layout: part[y][k][NLANE], k: 0..15 S, 16..31 T, 32 deg
__global__ __launch_bounds__(256) void accum_kernel(
    const float* __restrict__ H, const float* __restrict__ p,
    float* __restrict__ part) {
  __shared__ float lp[VCH * 32];   // 62.5 KB
  int b = blockIdx.x;
  // NBLK=500: blocks 0..495 swizzle bijectively (8 XCD slabs of 62), rest identity
  int item;
  if (b < 496) item = (b & 7) * 62 + (b >> 3);
  else         item = b;
  int xb = item % NXB;
  int y  = item / NXB;
  int e0 = 4 * (xb * 256 + (int)threadIdx.x);
  if (e0 > NE - 4) e0 = NE - 4;   // dup lanes write identical values: benign
  int v0 = y * VCH;

  // stage the p slice (contiguous 64 KB) into LDS, coalesced float4
  {
    const float4* __restrict__ src = (const float4*)(p + (size_t)v0 * 32);
    float4* dst = (float4*)lp;
    for (int i = threadIdx.x; i < VCH * 8; i += 256) dst[i] = src[i];
  }
  __syncthreads();

  float4 aS[16], aT[16], dg;
#pragma unroll
  for (int k = 0; k < 16; ++k) {
    aS[k] = make_float4(0.f, 0.f, 0.f, 0.f);
    aT[k] = make_float4(0.f, 0.f, 0.f, 0.f);
  }
  dg = make_float4(0.f, 0.f, 0.f, 0.f);

  const float* __restrict__ hp = H + (size_t)v0 * NE + e0;

  vf4 hc[GRP];
#pragma unroll
  for (int u = 0; u < GRP; ++u)
    hc[u] = __builtin_nontemporal_load((const vf4*)(hp + (size_t)u * NE));

  for (int vb = 0; vb < VCH; vb += GRP) {
    int nb = (vb + GRP < VCH) ? vb + GRP : vb;   // last iter: benign re-load
    vf4 hn[GRP];
#pragma unroll
    for (int u = 0; u < GRP; ++u)
      hn[u] = __builtin_nontemporal_load((const vf4*)(hp + (size_t)(nb + u) * NE));

#pragma unroll
    for (int u = 0; u < GRP; ++u) {
      const float4* __restrict__ r = (const float4*)(lp + (size_t)(vb + u) * 32);
      vf4 h = hc[u];
      dg.x += h.x; dg.y += h.y; dg.z += h.z; dg.w += h.w;
      {
        float4 s0 = r[0], s1 = r[1], s2 = r[2], s3 = r[3];
        float sv[16] = {s0.x,s0.y,s0.z,s0.w, s1.x,s1.y,s1.z,s1.w,
                        s2.x,s2.y,s2.z,s2.w, s3.x,s3.y,s3.z,s3.w};
#pragma unroll
        for (int k = 0; k < 16; ++k) {
          aS[k].x = fmaf(h.x, sv[k], aS[k].x);
          aS[k].y = fmaf(h.y, sv[k], aS[k].y);
          aS[k].z = fmaf(h.z, sv[k], aS[k].z);
          aS[k].w = fmaf(h.w, sv[k], aS[k].w);
        }
      }
      {
        float4 t0 = r[4], t1 = r[5], t2 = r[6], t3 = r[7];
        float tv[16] = {t0.x,t0.y,t0.z,t0.w, t1.x,t1.y,t1.z,t1.w,
                        t2.x,t2.y,t2.z,t2.w, t3.x,t3.y,t3.z,t3.w};
#pragma unroll
        for (int k = 0; k < 16; ++k) {
          aT[k].x = fmaf(h.x, tv[k], aT[k].x);
          aT[k].y = fmaf(h.y, tv[k], aT[k].y);
          aT[k].z = fmaf(h.z, tv[k], aT[k].z);
          aT[k].w = fmaf(h.w, tv[k], aT[k].w);
        }
      }
    }
#pragma unroll
    for (int u = 0; u < GRP; ++u) hc[u] = hn[u];
  }

  float* op = part + (size_t)y * 33 * NLANE + e0;
#pragma unroll
  for (int k = 0; k < 16; ++k) {
    vf4 w = {aS[k].x, aS[k].y, aS[k].z, aS[k].w};
    __builtin_nontemporal_store(w, (vf4*)(op + (size_t)k * NLANE));
  }
#pragma unroll
  for (int k = 0; k < 16; ++k) {
    vf4 w = {aT[k].x, aT[k].y, aT[k].z, aT[k].w};
    __builtin_nontemporal_store(w, (vf4*)(op + (size_t)(16 + k) * NLANE));
  }
  {
    vf4 w = {dg.x, dg.y, dg.z, dg.w};
    __builtin_nontemporal_store(w, (vf4*)(op + (size_t)32 * NLANE));
  }
}

// ---------------- reduce the NCH partials: acc[k][NLANE] = sum_y part[y][k][NLANE]
__global__ __launch_bounds__(256) void reduce_kernel(
    const float* __restrict__ part, float* __restrict__ acc) {
  int i = blockIdx.x * 256 + threadIdx.x;
  if (i >= 33 * NLANE) return;
  float s = 0.f;
#pragma unroll 4
  for (int y = 0; y < NCH; ++y)
    s += __builtin_nontemporal_load(part + (size_t)y * 33 * NLANE + i);
  acc[i] = s;
}

// ---------------- per-edge KL + masked reduction (single block, 256 threads)
// acc layout: acc[k*NLANE + e]; S at k, T at 16+k, deg at 32
__global__ __launch_bounds__(256) void kl_kernel(
    const float* __restrict__ acc, const unsigned char* __restrict__ e_mask,
    float* __restrict__ out) {
  __shared__ float snum[4];
  __shared__ float scnt[4];
  int t = threadIdx.x;
  float num = 0.f, cnt = 0.f;
  for (int e = t; e < NE; e += 256) {
    if (e_mask[e]) {
      float deg = acc[(size_t)32 * NLANE + e];
      float invd = 1.f / deg;
      float kl = 0.f;
#pragma unroll
      for (int k = 0; k < 16; ++k) {
        float ms = acc[(size_t)k * NLANE + e] * invd;
        float mt = acc[(size_t)(16 + k) * NLANE + e] * invd;
        float xs = ms * TAU_INV + EPS;
        float xt = mt * TAU_INV + EPS;
        kl += xt * (logf(xt) - logf(xs));
      }
      num += kl;
      cnt += 1.f;
    }
  }
#pragma unroll
  for (int off = 32; off > 0; off >>= 1) {
    num += __shfl_down(num, off, 64);
    cnt += __shfl_down(cnt, off, 64);
  }
  if ((t & 63) == 0) { snum[t >> 6] = num; scnt[t >> 6] = cnt; }
  __syncthreads();
  if (t == 0) {
    float n = snum[0] + snum[1] + snum[2] + snum[3];
    float c2 = scnt[0] + scnt[1] + scnt[2] + scnt[3];
    out[0] = n / fmaxf(c2, 1.f);
  }
}

extern "C" void kernel_launch(void* const* d_in, const int* in_sizes, int n_in,
                              void* d_out, int out_size, void* d_ws, size_t ws_size,
                              hipStream_t stream) {
  const float* pred_s = (const float*)d_in[0];
  const float* pred_t = (const float*)d_in[1];
  const float* H      = (const float*)d_in[2];
  const unsigned char* e_mask = (const unsigned char*)d_in[3];

  float* ws   = (float*)d_ws;
  float* p    = ws;                                    // NV*32         (6.40 MB)
  float* acc  = ws + (size_t)NV * 32;                  // 33*NLANE      (0.68 MB)
  float* part = acc + (size_t)33 * NLANE;              // NCH*33*NLANE  (67.6 MB)

  softmax_kernel<<<dim3((2 * NV + 255) / 256), 256, 0, stream>>>(pred_s, pred_t, p);
  accum_kernel<<<dim3(NBLK), 256, 0, stream>>>(H, p, part);
  reduce_kernel<<<dim3((33 * NLANE + 255) / 256), 256, 0, stream>>>(part, acc);
  kl_kernel<<<1, 256, 0, stream>>>(acc, e_mask, (float*)d_out);
}